// Round 1
// baseline (1937.503 us; speedup 1.0000x reference)
//
#include <hip/hip_runtime.h>
#include <hip/hip_bf16.h>
#include <cstdint>

// ---- problem constants ----
#define B_   2
#define L_   1024
#define H_   768
#define DI_  1536
#define DI2_ 3072      // 2*DI
#define DUP_ 12288     // 2*DI*4
#define DOUT_ 6144     // 4*DI
#define N_   16
#define R_   48
#define RN2_ 80        // R + 2N
#define BL_  2048      // B*L

typedef __bf16 bf16x8 __attribute__((ext_vector_type(8)));
typedef float  f32x4  __attribute__((ext_vector_type(4)));

__device__ __forceinline__ float silu_f(float v) {
    return v / (1.f + __expf(-v));
}

// ---------------------------------------------------------------------------
// bf16 MFMA GEMM, NT layout: Out[m,n] = sum_k A[m,k] * W[n,k]
// A: M x lda (fp32, row-major, k contiguous), W: N x ldw (fp32, row-major, k contiguous)
// 128x128 tile, BK=32, 256 threads (4 waves, each a 64x64 quadrant, 4x4 mfma tiles)
// blockIdx.z = split-K slice; slice z covers k in [z*Kslice, (z+1)*Kslice),
// writes to O + z*M*ldo (partials land in consecutive buffers).
// EPI: 0 = plain store, 1 = silu store
// ---------------------------------------------------------------------------
template<int EPI>
__global__ __launch_bounds__(256) void gemm_nt(
    const float* __restrict__ A, const float* __restrict__ W, float* __restrict__ O,
    int M, int N, int Kslice, int lda, int ldw, int ldo)
{
    constexpr int BM = 128, BN = 128, BK = 32, LR = 40;  // LR: bf16 per LDS row (32 data + 8 pad)
    __shared__ __bf16 As[BM * LR];
    __shared__ __bf16 Bs[BN * LR];

    const int tid  = threadIdx.x;
    const int bm   = blockIdx.x * BM;
    const int bn   = blockIdx.y * BN;
    const int kbase = blockIdx.z * Kslice;
    O += (size_t)blockIdx.z * (size_t)M * (size_t)ldo;

    const int wave = tid >> 6, lane = tid & 63;
    const int wm = (wave >> 1) * 64, wn = (wave & 1) * 64;
    const int quad = lane >> 4, tr = lane & 15;

    // staging: thread -> (row, 16-wide k chunk)
    const int srow = tid >> 1;
    const int skq  = (tid & 1) * 16;

    const float* Ag = A + (size_t)(bm + srow) * lda + kbase + skq;
    const float* Wg = W + (size_t)(bn + srow) * ldw + kbase + skq;
    __bf16* asp = &As[srow * LR + skq];
    __bf16* bsp = &Bs[srow * LR + skq];
    const __bf16* arp = &As[(wm + tr) * LR + quad * 8];
    const __bf16* brp = &Bs[(wn + tr) * LR + quad * 8];

    f32x4 acc[4][4];
#pragma unroll
    for (int i = 0; i < 4; ++i)
#pragma unroll
        for (int j = 0; j < 4; ++j) acc[i][j] = (f32x4){0.f, 0.f, 0.f, 0.f};

    for (int k0 = 0; k0 < Kslice; k0 += BK) {
        float4 a0 = *(const float4*)(Ag + k0);
        float4 a1 = *(const float4*)(Ag + k0 + 4);
        float4 a2 = *(const float4*)(Ag + k0 + 8);
        float4 a3 = *(const float4*)(Ag + k0 + 12);
        float4 b0 = *(const float4*)(Wg + k0);
        float4 b1 = *(const float4*)(Wg + k0 + 4);
        float4 b2 = *(const float4*)(Wg + k0 + 8);
        float4 b3 = *(const float4*)(Wg + k0 + 12);

        __syncthreads();   // previous iteration's LDS reads done
        bf16x8 av0, av1, bv0, bv1;
        av0[0]=(__bf16)a0.x; av0[1]=(__bf16)a0.y; av0[2]=(__bf16)a0.z; av0[3]=(__bf16)a0.w;
        av0[4]=(__bf16)a1.x; av0[5]=(__bf16)a1.y; av0[6]=(__bf16)a1.z; av0[7]=(__bf16)a1.w;
        av1[0]=(__bf16)a2.x; av1[1]=(__bf16)a2.y; av1[2]=(__bf16)a2.z; av1[3]=(__bf16)a2.w;
        av1[4]=(__bf16)a3.x; av1[5]=(__bf16)a3.y; av1[6]=(__bf16)a3.z; av1[7]=(__bf16)a3.w;
        bv0[0]=(__bf16)b0.x; bv0[1]=(__bf16)b0.y; bv0[2]=(__bf16)b0.z; bv0[3]=(__bf16)b0.w;
        bv0[4]=(__bf16)b1.x; bv0[5]=(__bf16)b1.y; bv0[6]=(__bf16)b1.z; bv0[7]=(__bf16)b1.w;
        bv1[0]=(__bf16)b2.x; bv1[1]=(__bf16)b2.y; bv1[2]=(__bf16)b2.z; bv1[3]=(__bf16)b2.w;
        bv1[4]=(__bf16)b3.x; bv1[5]=(__bf16)b3.y; bv1[6]=(__bf16)b3.z; bv1[7]=(__bf16)b3.w;
        *(bf16x8*)asp       = av0;
        *(bf16x8*)(asp + 8) = av1;
        *(bf16x8*)bsp       = bv0;
        *(bf16x8*)(bsp + 8) = bv1;
        __syncthreads();

        bf16x8 af[4], bfv[4];
#pragma unroll
        for (int i = 0; i < 4; ++i) af[i]  = *(const bf16x8*)(arp + i * 16 * LR);
#pragma unroll
        for (int j = 0; j < 4; ++j) bfv[j] = *(const bf16x8*)(brp + j * 16 * LR);
#pragma unroll
        for (int i = 0; i < 4; ++i)
#pragma unroll
            for (int j = 0; j < 4; ++j)
                acc[i][j] = __builtin_amdgcn_mfma_f32_16x16x32_bf16(af[i], bfv[j], acc[i][j], 0, 0, 0);
    }

    // epilogue: D[row=quad*4+r][col=lane&15]  (measured C/D layout, learn_hip m89/m91)
#pragma unroll
    for (int i = 0; i < 4; ++i) {
        const int row = bm + wm + i * 16 + quad * 4;
#pragma unroll
        for (int j = 0; j < 4; ++j) {
            const int col = bn + wn + j * 16 + tr;
            float* op = O + (size_t)row * ldo + col;
#pragma unroll
            for (int r = 0; r < 4; ++r) {
                float v = acc[i][j][r];
                if (EPI == 1) v = silu_f(v);
                op[(size_t)r * ldo] = v;
            }
        }
    }
}

// ---------------------------------------------------------------------------
// depthwise causal conv (K=4) + bias + silu.  P = P0 + P1 (split-K partials of G2).
// hs[b,l,d] = silu(conv_b[d] + sum_k cw[d,k] * P[b, l-3+k, d]),  d < DI cols of P
// output HS layout [b*L + l][DI]
// ---------------------------------------------------------------------------
__global__ void conv_kernel(const float* __restrict__ P0, const float* __restrict__ P1,
                            const float* __restrict__ cw, const float* __restrict__ cb,
                            float* __restrict__ HS)
{
    const int t = blockIdx.x * blockDim.x + threadIdx.x;  // < BL*DI
    const int d = t % DI_;
    const int bl = t / DI_;
    const int l = bl % L_;
    const float4 w = *(const float4*)(cw + (size_t)d * 4);
    const float wk[4] = {w.x, w.y, w.z, w.w};
    float acc = cb[d];
#pragma unroll
    for (int k = 0; k < 4; ++k) {
        const int ls = l - 3 + k;
        if (ls >= 0) {
            const size_t idx = (size_t)(bl - l + ls) * DI2_ + d;
            acc += wk[k] * (P0[idx] + P1[idx]);
        }
    }
    HS[t] = silu_f(acc);
}

// ---------------------------------------------------------------------------
// ssm_p[bl, j] = sum_d HS[bl, d] * x_proj_w[j, d]   (j < 80)
// ---------------------------------------------------------------------------
__global__ void ssm_proj_kernel(const float* __restrict__ HS, const float* __restrict__ XP,
                                float* __restrict__ SP)
{
    const int t = blockIdx.x * blockDim.x + threadIdx.x;  // < BL*RN2
    const int j = t % RN2_;
    const int bl = t / RN2_;
    const float4* h  = (const float4*)(HS + (size_t)bl * DI_);
    const float4* xp = (const float4*)(XP + (size_t)j * DI_);
    float s = 0.f;
#pragma unroll 4
    for (int i = 0; i < DI_ / 4; ++i) {
        const float4 a = h[i], b = xp[i];
        s += a.x * b.x + a.y * b.y + a.z * b.z + a.w * b.w;
    }
    SP[t] = s;
}

// ---------------------------------------------------------------------------
// dt[bl, d] = softplus(sum_r ts[bl, r] * dt_w[d, r] + dt_b[d]),  ts = SP[:, :48]
// ---------------------------------------------------------------------------
__global__ void dt_kernel(const float* __restrict__ SP, const float* __restrict__ dtw,
                          const float* __restrict__ dtb, float* __restrict__ DT)
{
    const int t = blockIdx.x * blockDim.x + threadIdx.x;  // < BL*DI
    const int d = t % DI_;
    const int bl = t / DI_;
    const float4* ts = (const float4*)(SP + (size_t)bl * RN2_);
    const float4* w  = (const float4*)(dtw + (size_t)d * R_);
    float s = dtb[d];
#pragma unroll
    for (int r = 0; r < R_ / 4; ++r) {
        const float4 a = ts[r], b = w[r];
        s += a.x * b.x + a.y * b.y + a.z * b.z + a.w * b.w;
    }
    DT[t] = (s > 20.f) ? s : log1pf(__expf(s));
}

// ---------------------------------------------------------------------------
// selective scan + skip (D) + gate.  16 lanes per (b,d) handle the N=16 states;
// shuffle-xor reduction over n.  gate = P[:, DI:, :] (split-K partials summed).
// Y[bl, d] = (sum_n s_n * C) + hs*D, gated by silu(gate)
// ---------------------------------------------------------------------------
__global__ void scan_kernel(const float* __restrict__ HS, const float* __restrict__ SP,
                            const float* __restrict__ DT, const float* __restrict__ P0,
                            const float* __restrict__ P1, const float* __restrict__ A_log,
                            const float* __restrict__ Dv, float* __restrict__ Y)
{
    const int gt = blockIdx.x * blockDim.x + threadIdx.x;  // < B*DI*16
    const int n = gt & (N_ - 1);
    const int pair = gt >> 4;
    const int d = pair % DI_;
    const int b = pair / DI_;
    const float A = -__expf(A_log[d * N_ + n]);
    const float Dd = Dv[d];
    float s = 0.f;
    for (int l = 0; l < L_; ++l) {
        const size_t bl = (size_t)b * L_ + l;
        const float dt = DT[bl * DI_ + d];
        const float hs = HS[bl * DI_ + d];
        const float Bv = SP[bl * RN2_ + R_ + n];
        const float Cv = SP[bl * RN2_ + R_ + N_ + n];
        const float dA = __expf(dt * A);
        s = fmaf(dA, s, dt * Bv * hs);
        float c = s * Cv;
        c += __shfl_xor(c, 1);
        c += __shfl_xor(c, 2);
        c += __shfl_xor(c, 4);
        c += __shfl_xor(c, 8);
        if (n == 0) {
            const size_t gi = bl * DI2_ + DI_ + d;
            const float g = P0[gi] + P1[gi];
            float y = c + hs * Dd;
            y *= silu_f(g);
            Y[bl * DI_ + d] = y;
        }
    }
}

// ---------------------------------------------------------------------------
// sum 4 split-K partials of G5 into d_out
// ---------------------------------------------------------------------------
__global__ void reduce4_kernel(const float* __restrict__ p, float* __restrict__ out, int n)
{
    const int i = blockIdx.x * blockDim.x + threadIdx.x;
    if (i < n)
        out[i] = p[i] + p[(size_t)i + n] + p[(size_t)i + 2 * (size_t)n] + p[(size_t)i + 3 * (size_t)n];
}

extern "C" void kernel_launch(void* const* d_in, const int* in_sizes, int n_in,
                              void* d_out, int out_size, void* d_ws, size_t ws_size,
                              hipStream_t stream) {
    const float* x        = (const float*)d_in[0];   // [B,L,H]
    const float* w_up     = (const float*)d_in[1];   // [12288,768]
    const float* w_down   = (const float*)d_in[2];   // [3072,12288]
    const float* conv_w   = (const float*)d_in[3];   // [1536,1,4]
    const float* conv_b   = (const float*)d_in[4];   // [1536]
    const float* x_proj_w = (const float*)d_in[5];   // [80,1536]
    const float* dt_w     = (const float*)d_in[6];   // [1536,48]
    const float* dt_b     = (const float*)d_in[7];   // [1536]
    const float* A_log    = (const float*)d_in[8];   // [1536,16]
    const float* Dvec     = (const float*)d_in[9];   // [1536]
    const float* w_oup    = (const float*)d_in[10];  // [6144,1536]
    const float* w_odown  = (const float*)d_in[11];  // [768,6144]
    float* out = (float*)d_out;

    // workspace layout (floats). Total = 47,349,760 f = 189.4 MB
    float* ws  = (float*)d_ws;
    float* U1  = ws;                                   // BL*DUP        = 25,165,824
    float* P0  = U1 + (size_t)BL_ * DUP_;              // BL*DI2        =  6,291,456
    float* P1  = P0 + (size_t)BL_ * DI2_;              // BL*DI2        =  6,291,456
    float* HS  = P1 + (size_t)BL_ * DI2_;              // BL*DI         =  3,145,728
    float* SPb = HS + (size_t)BL_ * DI_;               // BL*RN2        =    163,840
    float* DTb = SPb + (size_t)BL_ * RN2_;             // BL*DI         =  3,145,728
    float* Yb  = DTb + (size_t)BL_ * DI_;              // BL*DI         =  3,145,728
    float* U2  = U1;                                   // BL*DOUT = 12,582,912 (U1 dead)
    float* G5p = P0;                                   // 4*BL*H = 6,291,456 (P dead)

    // G1: U1 = silu(x @ w_up^T)      [2048 x 12288], K=768
    gemm_nt<1><<<dim3(BL_ / 128, DUP_ / 128, 1), 256, 0, stream>>>(
        x, w_up, U1, BL_, DUP_, H_, H_, H_, DUP_);
    // G2: P = U1 @ w_down^T          [2048 x 3072], K=12288, split-K x2 -> P0,P1
    gemm_nt<0><<<dim3(BL_ / 128, DI2_ / 128, 2), 256, 0, stream>>>(
        U1, w_down, P0, BL_, DI2_, DUP_ / 2, DUP_, DUP_, DI2_);
    // conv + silu -> HS [bl][d]
    conv_kernel<<<(BL_ * DI_) / 256, 256, 0, stream>>>(P0, P1, conv_w, conv_b, HS);
    // ssm projection -> SP [bl][80]
    ssm_proj_kernel<<<(BL_ * RN2_) / 256, 256, 0, stream>>>(HS, x_proj_w, SPb);
    // dt = softplus(ts @ dt_w^T + dt_b) -> DT [bl][d]
    dt_kernel<<<(BL_ * DI_) / 256, 256, 0, stream>>>(SPb, dt_w, dt_b, DTb);
    // selective scan + D skip + gate -> Y [bl][d]
    scan_kernel<<<(B_ * DI_ * N_) / 256, 256, 0, stream>>>(
        HS, SPb, DTb, P0, P1, A_log, Dvec, Yb);
    // G4: U2 = silu(Y @ w_oup^T)     [2048 x 6144], K=1536
    gemm_nt<1><<<dim3(BL_ / 128, DOUT_ / 128, 1), 256, 0, stream>>>(
        Yb, w_oup, U2, BL_, DOUT_, DI_, DI_, DI_, DOUT_);
    // G5: out = U2 @ w_odown^T       [2048 x 768], K=6144, split-K x4 -> G5p
    gemm_nt<0><<<dim3(BL_ / 128, H_ / 128, 4), 256, 0, stream>>>(
        U2, w_odown, G5p, BL_, H_, DOUT_ / 4, DOUT_, DOUT_, H_);
    // reduce 4 partials -> d_out
    reduce4_kernel<<<(BL_ * H_) / 256, 256, 0, stream>>>(G5p, out, BL_ * H_);
}

// Round 2
// 1311.119 us; speedup vs baseline: 1.4777x; 1.4777x over previous
//
#include <hip/hip_runtime.h>
#include <hip/hip_bf16.h>
#include <cstdint>

// ---- problem constants ----
#define B_   2
#define L_   1024
#define H_   768
#define DI_  1536
#define DI2_ 3072      // 2*DI
#define DUP_ 12288     // 2*DI*4
#define DOUT_ 6144     // 4*DI
#define N_   16
#define R_   48
#define RN2_ 80        // R + 2N
#define BL_  2048      // B*L
#define C_   16        // scan chunks
#define CL_  64        // L_/C_ steps per chunk

typedef __bf16 bf16x8 __attribute__((ext_vector_type(8)));
typedef float  f32x4  __attribute__((ext_vector_type(4)));

__device__ __forceinline__ float silu_f(float v) {
    return v / (1.f + __expf(-v));
}

// ---------------------------------------------------------------------------
// bf16 MFMA GEMM, NT layout: Out[m,n] = sum_k A[m,k] * W[n,k]
// (unchanged from round 1 — see round-2 plan for bf16/global_load_lds rework)
// ---------------------------------------------------------------------------
template<int EPI>
__global__ __launch_bounds__(256) void gemm_nt(
    const float* __restrict__ A, const float* __restrict__ W, float* __restrict__ O,
    int M, int N, int Kslice, int lda, int ldw, int ldo)
{
    constexpr int BM = 128, BN = 128, BK = 32, LR = 40;
    __shared__ __bf16 As[BM * LR];
    __shared__ __bf16 Bs[BN * LR];

    const int tid  = threadIdx.x;
    const int bm   = blockIdx.x * BM;
    const int bn   = blockIdx.y * BN;
    const int kbase = blockIdx.z * Kslice;
    O += (size_t)blockIdx.z * (size_t)M * (size_t)ldo;

    const int wave = tid >> 6, lane = tid & 63;
    const int wm = (wave >> 1) * 64, wn = (wave & 1) * 64;
    const int quad = lane >> 4, tr = lane & 15;

    const int srow = tid >> 1;
    const int skq  = (tid & 1) * 16;

    const float* Ag = A + (size_t)(bm + srow) * lda + kbase + skq;
    const float* Wg = W + (size_t)(bn + srow) * ldw + kbase + skq;
    __bf16* asp = &As[srow * LR + skq];
    __bf16* bsp = &Bs[srow * LR + skq];
    const __bf16* arp = &As[(wm + tr) * LR + quad * 8];
    const __bf16* brp = &Bs[(wn + tr) * LR + quad * 8];

    f32x4 acc[4][4];
#pragma unroll
    for (int i = 0; i < 4; ++i)
#pragma unroll
        for (int j = 0; j < 4; ++j) acc[i][j] = (f32x4){0.f, 0.f, 0.f, 0.f};

    for (int k0 = 0; k0 < Kslice; k0 += BK) {
        float4 a0 = *(const float4*)(Ag + k0);
        float4 a1 = *(const float4*)(Ag + k0 + 4);
        float4 a2 = *(const float4*)(Ag + k0 + 8);
        float4 a3 = *(const float4*)(Ag + k0 + 12);
        float4 b0 = *(const float4*)(Wg + k0);
        float4 b1 = *(const float4*)(Wg + k0 + 4);
        float4 b2 = *(const float4*)(Wg + k0 + 8);
        float4 b3 = *(const float4*)(Wg + k0 + 12);

        __syncthreads();
        bf16x8 av0, av1, bv0, bv1;
        av0[0]=(__bf16)a0.x; av0[1]=(__bf16)a0.y; av0[2]=(__bf16)a0.z; av0[3]=(__bf16)a0.w;
        av0[4]=(__bf16)a1.x; av0[5]=(__bf16)a1.y; av0[6]=(__bf16)a1.z; av0[7]=(__bf16)a1.w;
        av1[0]=(__bf16)a2.x; av1[1]=(__bf16)a2.y; av1[2]=(__bf16)a2.z; av1[3]=(__bf16)a2.w;
        av1[4]=(__bf16)a3.x; av1[5]=(__bf16)a3.y; av1[6]=(__bf16)a3.z; av1[7]=(__bf16)a3.w;
        bv0[0]=(__bf16)b0.x; bv0[1]=(__bf16)b0.y; bv0[2]=(__bf16)b0.z; bv0[3]=(__bf16)b0.w;
        bv0[4]=(__bf16)b1.x; bv0[5]=(__bf16)b1.y; bv0[6]=(__bf16)b1.z; bv0[7]=(__bf16)b1.w;
        bv1[0]=(__bf16)b2.x; bv1[1]=(__bf16)b2.y; bv1[2]=(__bf16)b2.z; bv1[3]=(__bf16)b2.w;
        bv1[4]=(__bf16)b3.x; bv1[5]=(__bf16)b3.y; bv1[6]=(__bf16)b3.z; bv1[7]=(__bf16)b3.w;
        *(bf16x8*)asp       = av0;
        *(bf16x8*)(asp + 8) = av1;
        *(bf16x8*)bsp       = bv0;
        *(bf16x8*)(bsp + 8) = bv1;
        __syncthreads();

        bf16x8 af[4], bfv[4];
#pragma unroll
        for (int i = 0; i < 4; ++i) af[i]  = *(const bf16x8*)(arp + i * 16 * LR);
#pragma unroll
        for (int j = 0; j < 4; ++j) bfv[j] = *(const bf16x8*)(brp + j * 16 * LR);
#pragma unroll
        for (int i = 0; i < 4; ++i)
#pragma unroll
            for (int j = 0; j < 4; ++j)
                acc[i][j] = __builtin_amdgcn_mfma_f32_16x16x32_bf16(af[i], bfv[j], acc[i][j], 0, 0, 0);
    }

#pragma unroll
    for (int i = 0; i < 4; ++i) {
        const int row = bm + wm + i * 16 + quad * 4;
#pragma unroll
        for (int j = 0; j < 4; ++j) {
            const int col = bn + wn + j * 16 + tr;
            float* op = O + (size_t)row * ldo + col;
#pragma unroll
            for (int r = 0; r < 4; ++r) {
                float v = acc[i][j][r];
                if (EPI == 1) v = silu_f(v);
                op[(size_t)r * ldo] = v;
            }
        }
    }
}

// ---------------------------------------------------------------------------
// depthwise causal conv (K=4) + bias + silu.
// ---------------------------------------------------------------------------
__global__ void conv_kernel(const float* __restrict__ P0, const float* __restrict__ P1,
                            const float* __restrict__ cw, const float* __restrict__ cb,
                            float* __restrict__ HS)
{
    const int t = blockIdx.x * blockDim.x + threadIdx.x;
    const int d = t % DI_;
    const int bl = t / DI_;
    const int l = bl % L_;
    const float4 w = *(const float4*)(cw + (size_t)d * 4);
    const float wk[4] = {w.x, w.y, w.z, w.w};
    float acc = cb[d];
#pragma unroll
    for (int k = 0; k < 4; ++k) {
        const int ls = l - 3 + k;
        if (ls >= 0) {
            const size_t idx = (size_t)(bl - l + ls) * DI2_ + d;
            acc += wk[k] * (P0[idx] + P1[idx]);
        }
    }
    HS[t] = silu_f(acc);
}

// ---------------------------------------------------------------------------
// ssm_p[bl, j] = sum_d HS[bl, d] * x_proj_w[j, d]   (j < 80)
// ---------------------------------------------------------------------------
__global__ void ssm_proj_kernel(const float* __restrict__ HS, const float* __restrict__ XP,
                                float* __restrict__ SP)
{
    const int t = blockIdx.x * blockDim.x + threadIdx.x;
    const int j = t % RN2_;
    const int bl = t / RN2_;
    const float4* h  = (const float4*)(HS + (size_t)bl * DI_);
    const float4* xp = (const float4*)(XP + (size_t)j * DI_);
    float s = 0.f;
#pragma unroll 4
    for (int i = 0; i < DI_ / 4; ++i) {
        const float4 a = h[i], b = xp[i];
        s += a.x * b.x + a.y * b.y + a.z * b.z + a.w * b.w;
    }
    SP[t] = s;
}

// ---------------------------------------------------------------------------
// dt[bl, d] = softplus(sum_r ts[bl, r] * dt_w[d, r] + dt_b[d])
// ---------------------------------------------------------------------------
__global__ void dt_kernel(const float* __restrict__ SP, const float* __restrict__ dtw,
                          const float* __restrict__ dtb, float* __restrict__ DT)
{
    const int t = blockIdx.x * blockDim.x + threadIdx.x;
    const int d = t % DI_;
    const int bl = t / DI_;
    const float4* ts = (const float4*)(SP + (size_t)bl * RN2_);
    const float4* w  = (const float4*)(dtw + (size_t)d * R_);
    float s = dtb[d];
#pragma unroll
    for (int r = 0; r < R_ / 4; ++r) {
        const float4 a = ts[r], b = w[r];
        s += a.x * b.x + a.y * b.y + a.z * b.z + a.w * b.w;
    }
    DT[t] = (s > 20.f) ? s : log1pf(__expf(s));
}

// ---------------------------------------------------------------------------
// Chunked parallel scan over L.  Recurrence s <- dA*s + dBu is linear, so
// chunk-compose: pass1 computes per-chunk (prod dA, chunk contribution);
// pass2 scans the C_ chunk summaries serially per (b,d,n); pass3 replays each
// chunk from its initial state and emits y with the n-reduction + gate.
// Thread index gt = ((b*C + c)*DI + d)*N + n  -> n fastest (shuffle groups).
// ---------------------------------------------------------------------------
__global__ __launch_bounds__(256) void scan_pass1(
    const float* __restrict__ DT, const float* __restrict__ HS,
    const float* __restrict__ SP, const float* __restrict__ A_log,
    float* __restrict__ Aprod, float* __restrict__ Bacc)
{
    const int gt = blockIdx.x * blockDim.x + threadIdx.x;   // < B*C*DI*N
    const int n = gt & (N_ - 1);
    const int x = gt >> 4;
    const int d = x % DI_;
    const int y = x / DI_;
    const int c = y % C_;
    const int b = y / C_;
    const float A = -__expf(A_log[d * N_ + n]);
    float ap = 1.f, bc = 0.f;
    const int l0 = c * CL_;
    for (int l = l0; l < l0 + CL_; ++l) {
        const size_t bl = (size_t)b * L_ + l;
        const float dt = DT[bl * DI_ + d];
        const float hs = HS[bl * DI_ + d];
        const float Bv = SP[bl * RN2_ + R_ + n];
        const float dA = __expf(dt * A);
        bc = fmaf(dA, bc, dt * Bv * hs);
        ap *= dA;
    }
    Aprod[gt] = ap;
    Bacc[gt]  = bc;
}

__global__ __launch_bounds__(256) void scan_pass2(
    const float* __restrict__ Aprod, const float* __restrict__ Bacc,
    float* __restrict__ Sinit)
{
    const int t = blockIdx.x * blockDim.x + threadIdx.x;    // < B*DI*N
    const int n = t & (N_ - 1);
    const int d = (t >> 4) % DI_;
    const int b = (t >> 4) / DI_;
    float s = 0.f;
#pragma unroll
    for (int c = 0; c < C_; ++c) {
        const size_t idx = (((size_t)b * C_ + c) * DI_ + d) * N_ + n;
        Sinit[idx] = s;
        s = fmaf(Aprod[idx], s, Bacc[idx]);
    }
}

__global__ __launch_bounds__(256) void scan_pass3(
    const float* __restrict__ DT, const float* __restrict__ HS,
    const float* __restrict__ SP, const float* __restrict__ P0,
    const float* __restrict__ P1, const float* __restrict__ A_log,
    const float* __restrict__ Dv, const float* __restrict__ Sinit,
    float* __restrict__ Y)
{
    const int gt = blockIdx.x * blockDim.x + threadIdx.x;   // < B*C*DI*N
    const int n = gt & (N_ - 1);
    const int x = gt >> 4;
    const int d = x % DI_;
    const int y = x / DI_;
    const int c = y % C_;
    const int b = y / C_;
    const float A = -__expf(A_log[d * N_ + n]);
    const float Dd = Dv[d];
    float s = Sinit[gt];
    const int l0 = c * CL_;
    for (int l = l0; l < l0 + CL_; ++l) {
        const size_t bl = (size_t)b * L_ + l;
        const float dt = DT[bl * DI_ + d];
        const float hs = HS[bl * DI_ + d];
        const float Bv = SP[bl * RN2_ + R_ + n];
        const float Cv = SP[bl * RN2_ + R_ + N_ + n];
        const float dA = __expf(dt * A);
        s = fmaf(dA, s, dt * Bv * hs);
        float cv = s * Cv;
        cv += __shfl_xor(cv, 1);
        cv += __shfl_xor(cv, 2);
        cv += __shfl_xor(cv, 4);
        cv += __shfl_xor(cv, 8);
        if (n == 0) {
            const size_t gi = bl * DI2_ + DI_ + d;
            const float g = P0[gi] + P1[gi];
            Y[bl * DI_ + d] = (cv + hs * Dd) * silu_f(g);
        }
    }
}

// ---------------------------------------------------------------------------
// sum 4 split-K partials of G5 into d_out
// ---------------------------------------------------------------------------
__global__ void reduce4_kernel(const float* __restrict__ p, float* __restrict__ out, int n)
{
    const int i = blockIdx.x * blockDim.x + threadIdx.x;
    if (i < n)
        out[i] = p[i] + p[(size_t)i + n] + p[(size_t)i + 2 * (size_t)n] + p[(size_t)i + 3 * (size_t)n];
}

extern "C" void kernel_launch(void* const* d_in, const int* in_sizes, int n_in,
                              void* d_out, int out_size, void* d_ws, size_t ws_size,
                              hipStream_t stream) {
    const float* x        = (const float*)d_in[0];
    const float* w_up     = (const float*)d_in[1];
    const float* w_down   = (const float*)d_in[2];
    const float* conv_w   = (const float*)d_in[3];
    const float* conv_b   = (const float*)d_in[4];
    const float* x_proj_w = (const float*)d_in[5];
    const float* dt_w     = (const float*)d_in[6];
    const float* dt_b     = (const float*)d_in[7];
    const float* A_log    = (const float*)d_in[8];
    const float* Dvec     = (const float*)d_in[9];
    const float* w_oup    = (const float*)d_in[10];
    const float* w_odown  = (const float*)d_in[11];
    float* out = (float*)d_out;

    // workspace layout (floats). Total = 47,349,760 f = 189.4 MB (same as R1)
    float* ws  = (float*)d_ws;
    float* U1  = ws;                                   // BL*DUP
    float* P0  = U1 + (size_t)BL_ * DUP_;              // BL*DI2
    float* P1  = P0 + (size_t)BL_ * DI2_;              // BL*DI2
    float* HS  = P1 + (size_t)BL_ * DI2_;              // BL*DI
    float* SPb = HS + (size_t)BL_ * DI_;               // BL*RN2
    float* DTb = SPb + (size_t)BL_ * RN2_;             // BL*DI
    float* Yb  = DTb + (size_t)BL_ * DI_;              // BL*DI
    float* U2  = U1;                                   // BL*DOUT (U1 dead after G2)
    float* G5p = P0;                                   // 4*BL*H (P dead after scan)
    // scan chunk-state arrays overlay the tail of the U1 region (dead between
    // G2 and G4; U2 only needs the first BL*DOUT floats and is written after
    // the scan finishes). 3 x 786,432 floats = 9.4 MB.
    const size_t SCN = (size_t)B_ * C_ * DI_ * N_;     // 786,432
    float* Aprod = U1 + (size_t)BL_ * DOUT_ + 1024;    // past U2's extent
    float* Bacc  = Aprod + SCN;
    float* Sinit = Bacc + SCN;

    // G1: U1 = silu(x @ w_up^T)      [2048 x 12288], K=768
    gemm_nt<1><<<dim3(BL_ / 128, DUP_ / 128, 1), 256, 0, stream>>>(
        x, w_up, U1, BL_, DUP_, H_, H_, H_, DUP_);
    // G2: P = U1 @ w_down^T          [2048 x 3072], K=12288, split-K x2
    gemm_nt<0><<<dim3(BL_ / 128, DI2_ / 128, 2), 256, 0, stream>>>(
        U1, w_down, P0, BL_, DI2_, DUP_ / 2, DUP_, DUP_, DI2_);
    // conv + silu -> HS
    conv_kernel<<<(BL_ * DI_) / 256, 256, 0, stream>>>(P0, P1, conv_w, conv_b, HS);
    // ssm projection -> SP
    ssm_proj_kernel<<<(BL_ * RN2_) / 256, 256, 0, stream>>>(HS, x_proj_w, SPb);
    // dt -> DT
    dt_kernel<<<(BL_ * DI_) / 256, 256, 0, stream>>>(SPb, dt_w, dt_b, DTb);
    // chunked scan: pass1 (chunk summaries) -> pass2 (chunk scan) -> pass3 (emit)
    scan_pass1<<<(int)(SCN / 256), 256, 0, stream>>>(DTb, HS, SPb, A_log, Aprod, Bacc);
    scan_pass2<<<(B_ * DI_ * N_) / 256, 256, 0, stream>>>(Aprod, Bacc, Sinit);
    scan_pass3<<<(int)(SCN / 256), 256, 0, stream>>>(
        DTb, HS, SPb, P0, P1, A_log, Dvec, Sinit, Yb);
    // G4: U2 = silu(Y @ w_oup^T)     [2048 x 6144], K=1536
    gemm_nt<1><<<dim3(BL_ / 128, DOUT_ / 128, 1), 256, 0, stream>>>(
        Yb, w_oup, U2, BL_, DOUT_, DI_, DI_, DI_, DOUT_);
    // G5: out = U2 @ w_odown^T       [2048 x 768], K=6144, split-K x4
    gemm_nt<0><<<dim3(BL_ / 128, H_ / 128, 4), 256, 0, stream>>>(
        U2, w_odown, G5p, BL_, H_, DOUT_ / 4, DOUT_, DOUT_, H_);
    // reduce partials -> d_out
    reduce4_kernel<<<(BL_ * H_) / 256, 256, 0, stream>>>(G5p, out, BL_ * H_);
}

// Round 3
// 1089.973 us; speedup vs baseline: 1.7776x; 1.2029x over previous
//
#include <hip/hip_runtime.h>
#include <hip/hip_bf16.h>
#include <cstdint>

// ---- problem constants ----
#define B_   2
#define L_   1024
#define H_   768
#define DI_  1536
#define DI2_ 3072      // 2*DI
#define DUP_ 12288     // 2*DI*4
#define DOUT_ 6144     // 4*DI
#define N_   16
#define R_   48
#define RN2_ 80        // R + 2N
#define BL_  2048      // B*L
#define C_   16        // scan chunks
#define CL_  64        // L_/C_ steps per chunk

typedef __bf16 bf16x8 __attribute__((ext_vector_type(8)));
typedef float  f32x4  __attribute__((ext_vector_type(4)));
typedef unsigned int u32;

__device__ __forceinline__ float silu_f(float v) {
    return v / (1.f + __expf(-v));
}

// async global->LDS, 16 bytes per lane (global_load_lds_dwordx4).
// LDS dest must be wave-uniform base + lane*16 — our slot mapping guarantees it.
__device__ __forceinline__ void async_ld16(const void* g, void* lds) {
    __builtin_amdgcn_global_load_lds(
        (const __attribute__((address_space(1))) u32*)g,
        (__attribute__((address_space(3))) u32*)lds, 16, 0, 0);
}

// ---------------------------------------------------------------------------
// fp32 -> bf16 conversion, 8 elems/thread
// ---------------------------------------------------------------------------
__global__ void cvt_bf16(const float* __restrict__ src, __bf16* __restrict__ dst, int n)
{
    const int i = (blockIdx.x * blockDim.x + threadIdx.x) * 8;
    if (i < n) {
        const float4 a = *(const float4*)(src + i);
        const float4 b = *(const float4*)(src + i + 4);
        bf16x8 v;
        v[0] = (__bf16)a.x; v[1] = (__bf16)a.y; v[2] = (__bf16)a.z; v[3] = (__bf16)a.w;
        v[4] = (__bf16)b.x; v[5] = (__bf16)b.y; v[6] = (__bf16)b.z; v[7] = (__bf16)b.w;
        *(bf16x8*)(dst + i) = v;
    }
}

// ---------------------------------------------------------------------------
// bf16 MFMA GEMM (m97 structure), NT: Out[m,n] = sum_k A[m,k]*W[n,k]
// A: M x lda bf16, W: N x ldw bf16. 128x128 tile, BK=32, 256 threads,
// global_load_lds width-16 staging into unpadded [128][32] bf16 LDS tiles.
// EPI: 1 = silu. ATOMIC: 1 = atomicAdd fp32 (split-K), else plain store.
// ---------------------------------------------------------------------------
template<int EPI, int ATOMIC, typename OutT>
__global__ __launch_bounds__(256) void gemm_bf16(
    const __bf16* __restrict__ A, const __bf16* __restrict__ W, OutT* __restrict__ O,
    int M, int N, int Kslice, int lda, int ldw, int ldo)
{
    constexpr int BM = 128, BN = 128, BK = 32;
    __shared__ __bf16 As[BM * BK];   // row-major, stride 32 (64 B) — unpadded for DMA
    __shared__ __bf16 Bs[BN * BK];

    const int tid  = threadIdx.x;
    const int bm   = blockIdx.x * BM;
    const int bn   = blockIdx.y * BN;
    const int kbase = blockIdx.z * Kslice;

    const int wave = tid >> 6, lane = tid & 63;
    const int wm = (wave >> 1) * 64, wn = (wave & 1) * 64;
    const int quad = lane >> 4, tr = lane & 15;

    // staging: slot s in [0,512), row = s>>2, kchunk = (s&3)*8 elems; lds off = s*8 elems.
    const int srow = tid >> 2;
    const int skc  = (tid & 3) * 8;
    const __bf16* Ag0 = A + (size_t)(bm + srow) * lda + kbase + skc;
    const __bf16* Ag1 = A + (size_t)(bm + srow + 64) * lda + kbase + skc;
    const __bf16* Wg0 = W + (size_t)(bn + srow) * ldw + kbase + skc;
    const __bf16* Wg1 = W + (size_t)(bn + srow + 64) * ldw + kbase + skc;
    __bf16* Al0 = &As[tid * 8];
    __bf16* Al1 = &As[2048 + tid * 8];
    __bf16* Bl0 = &Bs[tid * 8];
    __bf16* Bl1 = &Bs[2048 + tid * 8];

    const __bf16* arp = &As[(wm + tr) * BK + quad * 8];
    const __bf16* brp = &Bs[(wn + tr) * BK + quad * 8];

    f32x4 acc[4][4];
#pragma unroll
    for (int i = 0; i < 4; ++i)
#pragma unroll
        for (int j = 0; j < 4; ++j) acc[i][j] = (f32x4){0.f, 0.f, 0.f, 0.f};

    for (int k0 = 0; k0 < Kslice; k0 += BK) {
        __syncthreads();                       // prior tile's LDS reads done
        async_ld16(Ag0 + k0, Al0);
        async_ld16(Ag1 + k0, Al1);
        async_ld16(Wg0 + k0, Bl0);
        async_ld16(Wg1 + k0, Bl1);
        __syncthreads();                       // vmcnt(0) drain + barrier

        bf16x8 af[4], bfv[4];
#pragma unroll
        for (int i = 0; i < 4; ++i) af[i]  = *(const bf16x8*)(arp + i * 16 * BK);
#pragma unroll
        for (int j = 0; j < 4; ++j) bfv[j] = *(const bf16x8*)(brp + j * 16 * BK);
#pragma unroll
        for (int i = 0; i < 4; ++i)
#pragma unroll
            for (int j = 0; j < 4; ++j)
                acc[i][j] = __builtin_amdgcn_mfma_f32_16x16x32_bf16(af[i], bfv[j], acc[i][j], 0, 0, 0);
    }

    // epilogue: D[row=quad*4+r][col=lane&15] (measured C/D layout, m89/m91)
#pragma unroll
    for (int i = 0; i < 4; ++i) {
        const int row = bm + wm + i * 16 + quad * 4;
#pragma unroll
        for (int j = 0; j < 4; ++j) {
            const int col = bn + wn + j * 16 + tr;
            OutT* op = O + (size_t)row * ldo + col;
#pragma unroll
            for (int r = 0; r < 4; ++r) {
                float v = acc[i][j][r];
                if (EPI == 1) v = silu_f(v);
                if (ATOMIC == 1) atomicAdd((float*)(op + (size_t)r * ldo), v);
                else             op[(size_t)r * ldo] = (OutT)v;
            }
        }
    }
}

// ---------------------------------------------------------------------------
// depthwise causal conv (K=4) + bias + silu.  P fp32 single buffer.
// ---------------------------------------------------------------------------
__global__ void conv_kernel(const float* __restrict__ P,
                            const float* __restrict__ cw, const float* __restrict__ cb,
                            float* __restrict__ HS)
{
    const int t = blockIdx.x * blockDim.x + threadIdx.x;
    const int d = t % DI_;
    const int bl = t / DI_;
    const int l = bl % L_;
    const float4 w = *(const float4*)(cw + (size_t)d * 4);
    const float wk[4] = {w.x, w.y, w.z, w.w};
    float acc = cb[d];
#pragma unroll
    for (int k = 0; k < 4; ++k) {
        const int ls = l - 3 + k;
        if (ls >= 0)
            acc += wk[k] * P[(size_t)(bl - l + ls) * DI2_ + d];
    }
    HS[t] = silu_f(acc);
}

// ---------------------------------------------------------------------------
// ssm_p[bl, j] = sum_d HS[bl, d] * x_proj_w[j, d]   (j < 80)
// ---------------------------------------------------------------------------
__global__ void ssm_proj_kernel(const float* __restrict__ HS, const float* __restrict__ XP,
                                float* __restrict__ SP)
{
    const int t = blockIdx.x * blockDim.x + threadIdx.x;
    const int j = t % RN2_;
    const int bl = t / RN2_;
    const float4* h  = (const float4*)(HS + (size_t)bl * DI_);
    const float4* xp = (const float4*)(XP + (size_t)j * DI_);
    float s = 0.f;
#pragma unroll 4
    for (int i = 0; i < DI_ / 4; ++i) {
        const float4 a = h[i], b = xp[i];
        s += a.x * b.x + a.y * b.y + a.z * b.z + a.w * b.w;
    }
    SP[t] = s;
}

// ---------------------------------------------------------------------------
// dt[bl, d] = softplus(sum_r ts[bl, r] * dt_w[d, r] + dt_b[d])
// ---------------------------------------------------------------------------
__global__ void dt_kernel(const float* __restrict__ SP, const float* __restrict__ dtw,
                          const float* __restrict__ dtb, float* __restrict__ DT)
{
    const int t = blockIdx.x * blockDim.x + threadIdx.x;
    const int d = t % DI_;
    const int bl = t / DI_;
    const float4* ts = (const float4*)(SP + (size_t)bl * RN2_);
    const float4* w  = (const float4*)(dtw + (size_t)d * R_);
    float s = dtb[d];
#pragma unroll
    for (int r = 0; r < R_ / 4; ++r) {
        const float4 a = ts[r], b = w[r];
        s += a.x * b.x + a.y * b.y + a.z * b.z + a.w * b.w;
    }
    DT[t] = (s > 20.f) ? s : log1pf(__expf(s));
}

// ---------------------------------------------------------------------------
// Chunked parallel scan (linear recurrence s <- dA*s + dBu).
// ---------------------------------------------------------------------------
__global__ __launch_bounds__(256) void scan_pass1(
    const float* __restrict__ DT, const float* __restrict__ HS,
    const float* __restrict__ SP, const float* __restrict__ A_log,
    float* __restrict__ Aprod, float* __restrict__ Bacc)
{
    const int gt = blockIdx.x * blockDim.x + threadIdx.x;   // < B*C*DI*N
    const int n = gt & (N_ - 1);
    const int x = gt >> 4;
    const int d = x % DI_;
    const int y = x / DI_;
    const int c = y % C_;
    const int b = y / C_;
    const float A = -__expf(A_log[d * N_ + n]);
    float ap = 1.f, bc = 0.f;
    const int l0 = c * CL_;
    for (int l = l0; l < l0 + CL_; ++l) {
        const size_t bl = (size_t)b * L_ + l;
        const float dt = DT[bl * DI_ + d];
        const float hs = HS[bl * DI_ + d];
        const float Bv = SP[bl * RN2_ + R_ + n];
        const float dA = __expf(dt * A);
        bc = fmaf(dA, bc, dt * Bv * hs);
        ap *= dA;
    }
    Aprod[gt] = ap;
    Bacc[gt]  = bc;
}

__global__ __launch_bounds__(256) void scan_pass2(
    const float* __restrict__ Aprod, const float* __restrict__ Bacc,
    float* __restrict__ Sinit)
{
    const int t = blockIdx.x * blockDim.x + threadIdx.x;    // < B*DI*N
    const int n = t & (N_ - 1);
    const int d = (t >> 4) % DI_;
    const int b = (t >> 4) / DI_;
    float s = 0.f;
#pragma unroll
    for (int c = 0; c < C_; ++c) {
        const size_t idx = (((size_t)b * C_ + c) * DI_ + d) * N_ + n;
        Sinit[idx] = s;
        s = fmaf(Aprod[idx], s, Bacc[idx]);
    }
}

__global__ __launch_bounds__(256) void scan_pass3(
    const float* __restrict__ DT, const float* __restrict__ HS,
    const float* __restrict__ SP, const float* __restrict__ P,
    const float* __restrict__ A_log, const float* __restrict__ Dv,
    const float* __restrict__ Sinit, __bf16* __restrict__ Y)
{
    const int gt = blockIdx.x * blockDim.x + threadIdx.x;   // < B*C*DI*N
    const int n = gt & (N_ - 1);
    const int x = gt >> 4;
    const int d = x % DI_;
    const int y = x / DI_;
    const int c = y % C_;
    const int b = y / C_;
    const float A = -__expf(A_log[d * N_ + n]);
    const float Dd = Dv[d];
    float s = Sinit[gt];
    const int l0 = c * CL_;
    for (int l = l0; l < l0 + CL_; ++l) {
        const size_t bl = (size_t)b * L_ + l;
        const float dt = DT[bl * DI_ + d];
        const float hs = HS[bl * DI_ + d];
        const float Bv = SP[bl * RN2_ + R_ + n];
        const float Cv = SP[bl * RN2_ + R_ + N_ + n];
        const float dA = __expf(dt * A);
        s = fmaf(dA, s, dt * Bv * hs);
        float cv = s * Cv;
        cv += __shfl_xor(cv, 1);
        cv += __shfl_xor(cv, 2);
        cv += __shfl_xor(cv, 4);
        cv += __shfl_xor(cv, 8);
        if (n == 0) {
            const float g = P[bl * DI2_ + DI_ + d];
            Y[bl * DI_ + d] = (__bf16)((cv + hs * Dd) * silu_f(g));
        }
    }
}

extern "C" void kernel_launch(void* const* d_in, const int* in_sizes, int n_in,
                              void* d_out, int out_size, void* d_ws, size_t ws_size,
                              hipStream_t stream) {
    const float* x        = (const float*)d_in[0];
    const float* w_up     = (const float*)d_in[1];
    const float* w_down   = (const float*)d_in[2];
    const float* conv_w   = (const float*)d_in[3];
    const float* conv_b   = (const float*)d_in[4];
    const float* x_proj_w = (const float*)d_in[5];
    const float* dt_w     = (const float*)d_in[6];
    const float* dt_b     = (const float*)d_in[7];
    const float* A_log    = (const float*)d_in[8];
    const float* Dvec     = (const float*)d_in[9];
    const float* w_oup    = (const float*)d_in[10];
    const float* w_odown  = (const float*)d_in[11];
    float* out = (float*)d_out;

    // ---- workspace (183.1 MB total; 189.4 MB proven safe in rounds 1-2) ----
    // R1 (25,165,824 B): x_b + wup_b  ->  P fp32 (after G1)  ->  woup_b (after pass3)
    // R2 (75,497,472 B): wdown_b
    // R3 (50,331,648 B): U1b  ->  U2b (first half) / scan state (second half)
    // R4 (12,582,912 B): HS fp32  ->  wodown_b (after pass3)
    // R5/R6/R7: SP, DT, Yb
    char* base = (char*)d_ws;
    __bf16* x_b     = (__bf16*)base;                          // 2048*768*2   = 3,145,728
    __bf16* wup_b   = (__bf16*)(base + 3145728);              // 12288*768*2  = 18,874,368
    float*  P       = (float*)base;                           // 2048*3072*4  = 25,165,824
    __bf16* woup_b  = (__bf16*)base;                          // 6144*1536*2  = 18,874,368
    char* r2 = base + 25165824;
    __bf16* wdown_b = (__bf16*)r2;                            // 3072*12288*2 = 75,497,472
    char* r3 = r2 + 75497472;
    __bf16* U1b     = (__bf16*)r3;                            // 2048*12288*2 = 50,331,648
    __bf16* U2b     = (__bf16*)r3;                            // 2048*6144*2  = 25,165,824
    const size_t SCN = (size_t)B_ * C_ * DI_ * N_;            // 786,432
    float* Aprod    = (float*)(r3 + 25165824);
    float* Bacc     = Aprod + SCN;
    float* Sinit    = Bacc + SCN;
    char* r4 = r3 + 50331648;
    float*  HS      = (float*)r4;                             // 2048*1536*4  = 12,582,912
    __bf16* wodown_b = (__bf16*)r4;                           // 768*6144*2   =  9,437,184
    char* r5 = r4 + 12582912;
    float*  SPb     = (float*)r5;                             // 2048*80*4    =    655,360
    char* r6 = r5 + 655360;
    float*  DTb     = (float*)r6;                             // 2048*1536*4  = 12,582,912
    char* r7 = r6 + 12582912;
    __bf16* Yb      = (__bf16*)r7;                            // 2048*1536*2  =  6,291,456

    // convert inputs/weights to bf16 (values identical to round-2's in-staging truncation)
    cvt_bf16<<<(BL_ * H_) / 2048, 256, 0, stream>>>(x, x_b, BL_ * H_);
    cvt_bf16<<<(DUP_ * H_) / 2048, 256, 0, stream>>>(w_up, wup_b, DUP_ * H_);
    cvt_bf16<<<(DI2_ * DUP_) / 2048, 256, 0, stream>>>(w_down, wdown_b, DI2_ * DUP_);

    // G1: U1b = silu(x @ w_up^T)  bf16 out   [2048 x 12288], K=768
    gemm_bf16<1, 0, __bf16><<<dim3(BL_ / 128, DUP_ / 128, 1), 256, 0, stream>>>(
        x_b, wup_b, U1b, BL_, DUP_, H_, H_, H_, DUP_);

    // P = U1 @ w_down^T  fp32 atomic, split-K x2   [2048 x 3072], K=12288
    hipMemsetAsync(P, 0, (size_t)BL_ * DI2_ * 4, stream);
    gemm_bf16<0, 1, float><<<dim3(BL_ / 128, DI2_ / 128, 2), 256, 0, stream>>>(
        U1b, wdown_b, P, BL_, DI2_, DUP_ / 2, DUP_, DUP_, DI2_);

    // conv + silu -> HS
    conv_kernel<<<(BL_ * DI_) / 256, 256, 0, stream>>>(P, conv_w, conv_b, HS);
    // ssm projection -> SP
    ssm_proj_kernel<<<(BL_ * RN2_) / 256, 256, 0, stream>>>(HS, x_proj_w, SPb);
    // dt -> DT
    dt_kernel<<<(BL_ * DI_) / 256, 256, 0, stream>>>(SPb, dt_w, dt_b, DTb);
    // chunked scan
    scan_pass1<<<(int)(SCN / 256), 256, 0, stream>>>(DTb, HS, SPb, A_log, Aprod, Bacc);
    scan_pass2<<<(B_ * DI_ * N_) / 256, 256, 0, stream>>>(Aprod, Bacc, Sinit);
    scan_pass3<<<(int)(SCN / 256), 256, 0, stream>>>(
        DTb, HS, SPb, P, A_log, Dvec, Sinit, Yb);

    // G4: U2b = silu(Y @ w_oup^T)  bf16 out   [2048 x 6144], K=1536
    cvt_bf16<<<(DOUT_ * DI_) / 2048, 256, 0, stream>>>(w_oup, woup_b, DOUT_ * DI_);
    gemm_bf16<1, 0, __bf16><<<dim3(BL_ / 128, DOUT_ / 128, 1), 256, 0, stream>>>(
        Yb, woup_b, U2b, BL_, DOUT_, DI_, DI_, DI_, DOUT_);

    // G5: out = U2 @ w_odown^T  fp32 atomic, split-K x4   [2048 x 768], K=6144
    cvt_bf16<<<(H_ * DOUT_) / 2048, 256, 0, stream>>>(w_odown, wodown_b, H_ * DOUT_);
    hipMemsetAsync(out, 0, (size_t)BL_ * H_ * 4, stream);
    gemm_bf16<0, 1, float><<<dim3(BL_ / 128, H_ / 128, 4), 256, 0, stream>>>(
        U2b, wodown_b, out, BL_, H_, DOUT_ / 4, DOUT_, DOUT_, H_);
}

// Round 4
// 860.032 us; speedup vs baseline: 2.2528x; 1.2674x over previous
//
#include <hip/hip_runtime.h>
#include <hip/hip_bf16.h>
#include <cstdint>

// ---- problem constants ----
#define B_   2
#define L_   1024
#define H_   768
#define DI_  1536
#define DI2_ 3072      // 2*DI
#define DUP_ 12288     // 2*DI*4
#define DOUT_ 6144     // 4*DI
#define N_   16
#define R_   48
#define SPW  128       // padded ssm_p row stride (R + 2N = 80 -> 128)
#define BL_  2048      // B*L
#define C_   64        // scan chunks
#define CL_  16        // L_/C_ steps per chunk

typedef __bf16 bf16x8 __attribute__((ext_vector_type(8)));
typedef float  f32x4  __attribute__((ext_vector_type(4)));
typedef unsigned int u32;

__device__ __forceinline__ float silu_f(float v) {
    return v / (1.f + __expf(-v));
}

__device__ __forceinline__ void async_ld16(const void* g, void* lds) {
    __builtin_amdgcn_global_load_lds(
        (const __attribute__((address_space(1))) u32*)g,
        (__attribute__((address_space(3))) u32*)lds, 16, 0, 0);
}

// ---------------------------------------------------------------------------
// fp32 -> bf16 conversion, 8 elems/thread
// ---------------------------------------------------------------------------
__global__ void cvt_bf16(const float* __restrict__ src, __bf16* __restrict__ dst, int n)
{
    const int i = (blockIdx.x * blockDim.x + threadIdx.x) * 8;
    if (i < n) {
        const float4 a = *(const float4*)(src + i);
        const float4 b = *(const float4*)(src + i + 4);
        bf16x8 v;
        v[0] = (__bf16)a.x; v[1] = (__bf16)a.y; v[2] = (__bf16)a.z; v[3] = (__bf16)a.w;
        v[4] = (__bf16)b.x; v[5] = (__bf16)b.y; v[6] = (__bf16)b.z; v[7] = (__bf16)b.w;
        *(bf16x8*)(dst + i) = v;
    }
}

// x_proj_w [80][1536] fp32 -> [128][1536] bf16 with rows 80..127 zeroed
__global__ void pad_xp(const float* __restrict__ xp, __bf16* __restrict__ dst)
{
    const int i = (blockIdx.x * blockDim.x + threadIdx.x) * 8;   // < 128*1536
    const int j = i / DI_;
    bf16x8 v;
    if (j < 80) {
        const float4 a = *(const float4*)(xp + i);
        const float4 b = *(const float4*)(xp + i + 4);
        v[0] = (__bf16)a.x; v[1] = (__bf16)a.y; v[2] = (__bf16)a.z; v[3] = (__bf16)a.w;
        v[4] = (__bf16)b.x; v[5] = (__bf16)b.y; v[6] = (__bf16)b.z; v[7] = (__bf16)b.w;
    } else {
        for (int k = 0; k < 8; ++k) v[k] = (__bf16)0.f;
    }
    *(bf16x8*)(dst + i) = v;
}

// dt_w [1536][48] -> dtwT [48][1536] fp32
__global__ void transpose_dtw(const float* __restrict__ w, float* __restrict__ wT)
{
    const int i = blockIdx.x * blockDim.x + threadIdx.x;   // < 48*1536
    const int r = i / DI_, d = i % DI_;
    wT[i] = w[(size_t)d * R_ + r];
}

// ---------------------------------------------------------------------------
// bf16 MFMA GEMM (m97 structure + XOR bank swizzle), NT: Out = A * W^T
// 128x128 tile, BK=32, 256 threads, global_load_lds width-16 staging.
// LDS k-chunk slot f of row r holds global chunk f ^ ((r>>1)&3): fragment
// reads become 2-way bank aliasing (free) instead of 8-way.
// ---------------------------------------------------------------------------
template<int EPI, int ATOMIC, typename OutT>
__global__ __launch_bounds__(256) void gemm_bf16(
    const __bf16* __restrict__ A, const __bf16* __restrict__ W, OutT* __restrict__ O,
    int M, int N, int Kslice, int lda, int ldw, int ldo)
{
    constexpr int BM = 128, BN = 128, BK = 32;
    __shared__ __bf16 As[BM * BK];
    __shared__ __bf16 Bs[BN * BK];

    const int tid  = threadIdx.x;
    const int bm   = blockIdx.x * BM;
    const int bn   = blockIdx.y * BN;
    const int kbase = blockIdx.z * Kslice;

    const int wave = tid >> 6, lane = tid & 63;
    const int wm = (wave >> 1) * 64, wn = (wave & 1) * 64;
    const int quad = lane >> 4, tr = lane & 15;

    // staging: thread (srow, c) stores global k-chunk c^((srow>>1)&3) into slot c
    const int srow = tid >> 2;
    const int skc  = ((tid & 3) ^ ((srow >> 1) & 3)) * 8;
    const __bf16* Ag0 = A + (size_t)(bm + srow) * lda + kbase + skc;
    const __bf16* Ag1 = A + (size_t)(bm + srow + 64) * lda + kbase + skc;
    const __bf16* Wg0 = W + (size_t)(bn + srow) * ldw + kbase + skc;
    const __bf16* Wg1 = W + (size_t)(bn + srow + 64) * ldw + kbase + skc;
    __bf16* Al0 = &As[tid * 8];
    __bf16* Al1 = &As[2048 + tid * 8];
    __bf16* Bl0 = &Bs[tid * 8];
    __bf16* Bl1 = &Bs[2048 + tid * 8];

    // fragment read: row (wm|wn)+tr, want global chunk `quad` -> slot quad^((tr>>1)&3)
    const int fsw = (quad ^ ((tr >> 1) & 3)) * 8;
    const __bf16* arp = &As[(wm + tr) * BK + fsw];
    const __bf16* brp = &Bs[(wn + tr) * BK + fsw];

    f32x4 acc[4][4];
#pragma unroll
    for (int i = 0; i < 4; ++i)
#pragma unroll
        for (int j = 0; j < 4; ++j) acc[i][j] = (f32x4){0.f, 0.f, 0.f, 0.f};

    for (int k0 = 0; k0 < Kslice; k0 += BK) {
        __syncthreads();
        async_ld16(Ag0 + k0, Al0);
        async_ld16(Ag1 + k0, Al1);
        async_ld16(Wg0 + k0, Bl0);
        async_ld16(Wg1 + k0, Bl1);
        __syncthreads();

        bf16x8 af[4], bfv[4];
#pragma unroll
        for (int i = 0; i < 4; ++i) af[i]  = *(const bf16x8*)(arp + i * 16 * BK);
#pragma unroll
        for (int j = 0; j < 4; ++j) bfv[j] = *(const bf16x8*)(brp + j * 16 * BK);
#pragma unroll
        for (int i = 0; i < 4; ++i)
#pragma unroll
            for (int j = 0; j < 4; ++j)
                acc[i][j] = __builtin_amdgcn_mfma_f32_16x16x32_bf16(af[i], bfv[j], acc[i][j], 0, 0, 0);
    }

    // epilogue: D[row=quad*4+r][col=lane&15] (m89/m91 layout)
#pragma unroll
    for (int i = 0; i < 4; ++i) {
        const int row = bm + wm + i * 16 + quad * 4;
#pragma unroll
        for (int j = 0; j < 4; ++j) {
            const int col = bn + wn + j * 16 + tr;
            OutT* op = O + (size_t)row * ldo + col;
#pragma unroll
            for (int r = 0; r < 4; ++r) {
                float v = acc[i][j][r];
                if (EPI == 1) v = silu_f(v);
                if (ATOMIC == 1) atomicAdd((float*)(op + (size_t)r * ldo), v);
                else             op[(size_t)r * ldo] = (OutT)v;
            }
        }
    }
}

// ---------------------------------------------------------------------------
// depthwise causal conv (K=4) + bias + silu; writes fp32 HS and bf16 HSb
// ---------------------------------------------------------------------------
__global__ void conv_kernel(const float* __restrict__ P,
                            const float* __restrict__ cw, const float* __restrict__ cb,
                            float* __restrict__ HS, __bf16* __restrict__ HSb)
{
    const int t = blockIdx.x * blockDim.x + threadIdx.x;
    const int d = t % DI_;
    const int bl = t / DI_;
    const int l = bl % L_;
    const float4 w = *(const float4*)(cw + (size_t)d * 4);
    const float wk[4] = {w.x, w.y, w.z, w.w};
    float acc = cb[d];
#pragma unroll
    for (int k = 0; k < 4; ++k) {
        const int ls = l - 3 + k;
        if (ls >= 0)
            acc += wk[k] * P[(size_t)(bl - l + ls) * DI2_ + d];
    }
    const float h = silu_f(acc);
    HS[t]  = h;
    HSb[t] = (__bf16)h;
}

// ---------------------------------------------------------------------------
// dt[bl, d] = softplus(sum_r ts[bl, r] * dtwT[r, d] + dt_b[d])
// coalesced weight reads + wave-uniform ts float4 loads
// ---------------------------------------------------------------------------
__global__ void dt_kernel(const float* __restrict__ SP, const float* __restrict__ dtwT,
                          const float* __restrict__ dtb, float* __restrict__ DT)
{
    const int t = blockIdx.x * blockDim.x + threadIdx.x;
    const int d = t % DI_;
    const int bl = t / DI_;
    const float* ts = SP + (size_t)bl * SPW;
    float s = dtb[d];
#pragma unroll
    for (int r4 = 0; r4 < R_ / 4; ++r4) {
        const float4 tv = *(const float4*)(ts + r4 * 4);
        const float* wp = dtwT + (size_t)r4 * 4 * DI_ + d;
        s += tv.x * wp[0] + tv.y * wp[DI_] + tv.z * wp[2 * DI_] + tv.w * wp[3 * DI_];
    }
    DT[t] = (s > 20.f) ? s : log1pf(__expf(s));
}

// ---------------------------------------------------------------------------
// Chunked parallel scan, thread per (b,c,d), 16 n-states in registers.
// All loads coalesced-over-d or wave-uniform float4 broadcasts.
// ---------------------------------------------------------------------------
__global__ __launch_bounds__(256) void scan_pass1(
    const float* __restrict__ DT, const float* __restrict__ HS,
    const float* __restrict__ SP, const float* __restrict__ A_log,
    float* __restrict__ Aprod, float* __restrict__ Bacc)
{
    const int t = blockIdx.x * blockDim.x + threadIdx.x;   // < B*C*DI
    const int d = t % DI_;
    const int y = t / DI_;
    const int c = y % C_;
    const int b = y / C_;
    float A[N_], s[N_], ap[N_];
    {
        const float4* alp = (const float4*)(A_log + (size_t)d * N_);
        const float4 a0 = alp[0], a1 = alp[1], a2 = alp[2], a3 = alp[3];
        const float av[N_] = {a0.x,a0.y,a0.z,a0.w, a1.x,a1.y,a1.z,a1.w,
                              a2.x,a2.y,a2.z,a2.w, a3.x,a3.y,a3.z,a3.w};
#pragma unroll
        for (int n = 0; n < N_; ++n) { A[n] = -__expf(av[n]); s[n] = 0.f; ap[n] = 1.f; }
    }
    for (int il = 0; il < CL_; ++il) {
        const size_t bl = (size_t)b * L_ + c * CL_ + il;
        const float dt = DT[bl * DI_ + d];
        const float hs = HS[bl * DI_ + d];
        const float4* Bp = (const float4*)(SP + bl * SPW + R_);
        const float4 b0 = Bp[0], b1 = Bp[1], b2 = Bp[2], b3 = Bp[3];
        const float Bv[N_] = {b0.x,b0.y,b0.z,b0.w, b1.x,b1.y,b1.z,b1.w,
                              b2.x,b2.y,b2.z,b2.w, b3.x,b3.y,b3.z,b3.w};
        const float dh = dt * hs;
#pragma unroll
        for (int n = 0; n < N_; ++n) {
            const float dA = __expf(dt * A[n]);
            s[n] = fmaf(dA, s[n], dh * Bv[n]);
            ap[n] *= dA;
        }
    }
    float4* Ap = (float4*)(Aprod + (size_t)t * N_);
    float4* Bc = (float4*)(Bacc  + (size_t)t * N_);
    Ap[0] = make_float4(ap[0], ap[1], ap[2], ap[3]);
    Ap[1] = make_float4(ap[4], ap[5], ap[6], ap[7]);
    Ap[2] = make_float4(ap[8], ap[9], ap[10], ap[11]);
    Ap[3] = make_float4(ap[12], ap[13], ap[14], ap[15]);
    Bc[0] = make_float4(s[0], s[1], s[2], s[3]);
    Bc[1] = make_float4(s[4], s[5], s[6], s[7]);
    Bc[2] = make_float4(s[8], s[9], s[10], s[11]);
    Bc[3] = make_float4(s[12], s[13], s[14], s[15]);
}

__global__ __launch_bounds__(256) void scan_pass2(
    const float* __restrict__ Aprod, const float* __restrict__ Bacc,
    float* __restrict__ Sinit)
{
    const int t = blockIdx.x * blockDim.x + threadIdx.x;    // < B*DI*N
    const int n = t & (N_ - 1);
    const int d = (t >> 4) % DI_;
    const int b = (t >> 4) / DI_;
    float s = 0.f;
    for (int c = 0; c < C_; ++c) {
        const size_t idx = (((size_t)b * C_ + c) * DI_ + d) * N_ + n;
        Sinit[idx] = s;
        s = fmaf(Aprod[idx], s, Bacc[idx]);
    }
}

__global__ __launch_bounds__(256) void scan_pass3(
    const float* __restrict__ DT, const float* __restrict__ HS,
    const float* __restrict__ SP, const float* __restrict__ P,
    const float* __restrict__ A_log, const float* __restrict__ Dv,
    const float* __restrict__ Sinit, __bf16* __restrict__ Y)
{
    const int t = blockIdx.x * blockDim.x + threadIdx.x;   // < B*C*DI
    const int d = t % DI_;
    const int y = t / DI_;
    const int c = y % C_;
    const int b = y / C_;
    float A[N_], s[N_];
    {
        const float4* alp = (const float4*)(A_log + (size_t)d * N_);
        const float4 a0 = alp[0], a1 = alp[1], a2 = alp[2], a3 = alp[3];
        const float av[N_] = {a0.x,a0.y,a0.z,a0.w, a1.x,a1.y,a1.z,a1.w,
                              a2.x,a2.y,a2.z,a2.w, a3.x,a3.y,a3.z,a3.w};
#pragma unroll
        for (int n = 0; n < N_; ++n) A[n] = -__expf(av[n]);
    }
    {
        const float4* sp = (const float4*)(Sinit + (size_t)t * N_);
        const float4 s0 = sp[0], s1 = sp[1], s2 = sp[2], s3 = sp[3];
        s[0]=s0.x; s[1]=s0.y; s[2]=s0.z; s[3]=s0.w;
        s[4]=s1.x; s[5]=s1.y; s[6]=s1.z; s[7]=s1.w;
        s[8]=s2.x; s[9]=s2.y; s[10]=s2.z; s[11]=s2.w;
        s[12]=s3.x; s[13]=s3.y; s[14]=s3.z; s[15]=s3.w;
    }
    const float Dd = Dv[d];
    for (int il = 0; il < CL_; ++il) {
        const size_t bl = (size_t)b * L_ + c * CL_ + il;
        const float dt = DT[bl * DI_ + d];
        const float hs = HS[bl * DI_ + d];
        const float4* Bp = (const float4*)(SP + bl * SPW + R_);
        const float4 b0 = Bp[0], b1 = Bp[1], b2 = Bp[2], b3 = Bp[3];
        const float4 c0 = Bp[4], c1 = Bp[5], c2 = Bp[6], c3 = Bp[7];
        const float Bv[N_] = {b0.x,b0.y,b0.z,b0.w, b1.x,b1.y,b1.z,b1.w,
                              b2.x,b2.y,b2.z,b2.w, b3.x,b3.y,b3.z,b3.w};
        const float Cv[N_] = {c0.x,c0.y,c0.z,c0.w, c1.x,c1.y,c1.z,c1.w,
                              c2.x,c2.y,c2.z,c2.w, c3.x,c3.y,c3.z,c3.w};
        const float dh = dt * hs;
        float acc = 0.f;
#pragma unroll
        for (int n = 0; n < N_; ++n) {
            const float dA = __expf(dt * A[n]);
            s[n] = fmaf(dA, s[n], dh * Bv[n]);
            acc = fmaf(s[n], Cv[n], acc);
        }
        const float g = P[bl * DI2_ + DI_ + d];
        Y[bl * DI_ + d] = (__bf16)((acc + hs * Dd) * silu_f(g));
    }
}

extern "C" void kernel_launch(void* const* d_in, const int* in_sizes, int n_in,
                              void* d_out, int out_size, void* d_ws, size_t ws_size,
                              hipStream_t stream) {
    const float* x        = (const float*)d_in[0];
    const float* w_up     = (const float*)d_in[1];
    const float* w_down   = (const float*)d_in[2];
    const float* conv_w   = (const float*)d_in[3];
    const float* conv_b   = (const float*)d_in[4];
    const float* x_proj_w = (const float*)d_in[5];
    const float* dt_w     = (const float*)d_in[6];
    const float* dt_b     = (const float*)d_in[7];
    const float* A_log    = (const float*)d_in[8];
    const float* Dvec     = (const float*)d_in[9];
    const float* w_oup    = (const float*)d_in[10];
    const float* w_odown  = (const float*)d_in[11];
    float* out = (float*)d_out;

    // ---- workspace layout, 163.6 MB total (183+ proven safe) ----
    // r1 (25,165,824): x_b + wup_b        -> P fp32 (after G1)
    // r2 (75,497,472): wdown_b            -> {HSb,SP,DT,Yb,XPpad,dtwT,woup_b,wodown_b} (after G2)
    // r3 (50,331,648): U1b                -> {Aprod,Bacc,Sinit}  -> U2b (G4)
    // r4 (12,582,912): HS fp32
    char* base = (char*)d_ws;
    __bf16* x_b      = (__bf16*)base;                      //  3,145,728
    __bf16* wup_b    = (__bf16*)(base + 3145728);          // 18,874,368
    float*  P        = (float*)base;                       // 25,165,824
    char* r2 = base + 25165824;
    __bf16* wdown_b  = (__bf16*)r2;                        // 75,497,472
    __bf16* HSb      = (__bf16*)r2;                        //  6,291,456
    float*  SPb      = (float*)(r2 + 6291456);             //  1,048,576 (2048*128*4)
    float*  DTb      = (float*)(r2 + 7340032);             // 12,582,912
    __bf16* Yb       = (__bf16*)(r2 + 19922944);           //  6,291,456
    __bf16* XPpad    = (__bf16*)(r2 + 26214400);           //    393,216
    float*  dtwT     = (float*)(r2 + 26607616);            //    294,912
    __bf16* woup_b   = (__bf16*)(r2 + 26902528);           // 18,874,368
    __bf16* wodown_b = (__bf16*)(r2 + 45776896);           //  9,437,184
    char* r3 = r2 + 75497472;
    __bf16* U1b      = (__bf16*)r3;                        // 50,331,648
    __bf16* U2b      = (__bf16*)r3;                        // 25,165,824
    float*  Aprod    = (float*)r3;                         // 12,582,912
    float*  Bacc     = (float*)(r3 + 12582912);            // 12,582,912
    float*  Sinit    = (float*)(r3 + 25165824);            // 12,582,912
    char* r4 = r3 + 50331648;
    float*  HS       = (float*)r4;                         // 12,582,912

    // bf16 inputs for G1/G2
    cvt_bf16<<<(BL_ * H_) / 2048, 256, 0, stream>>>(x, x_b, BL_ * H_);
    cvt_bf16<<<(DUP_ * H_) / 2048, 256, 0, stream>>>(w_up, wup_b, DUP_ * H_);
    cvt_bf16<<<(DI2_ * DUP_) / 2048, 256, 0, stream>>>(w_down, wdown_b, DI2_ * DUP_);

    // G1: U1b = silu(x @ w_up^T)   [2048 x 12288], K=768
    gemm_bf16<1, 0, __bf16><<<dim3(16, 96, 1), 256, 0, stream>>>(
        x_b, wup_b, U1b, BL_, DUP_, H_, H_, H_, DUP_);

    // G2: P = U1 @ w_down^T  fp32 atomic, split-K x4   [2048 x 3072], K=12288
    hipMemsetAsync(P, 0, (size_t)BL_ * DI2_ * 4, stream);
    gemm_bf16<0, 1, float><<<dim3(16, 24, 4), 256, 0, stream>>>(
        U1b, wdown_b, P, BL_, DI2_, DUP_ / 4, DUP_, DUP_, DI2_);

    // wdown_b dead from here: build small operand copies in r2
    pad_xp<<<(128 * DI_) / 2048, 256, 0, stream>>>(x_proj_w, XPpad);
    transpose_dtw<<<(R_ * DI_) / 256, 256, 0, stream>>>(dt_w, dtwT);
    cvt_bf16<<<(DOUT_ * DI_) / 2048, 256, 0, stream>>>(w_oup, woup_b, DOUT_ * DI_);
    cvt_bf16<<<(H_ * DOUT_) / 2048, 256, 0, stream>>>(w_odown, wodown_b, H_ * DOUT_);

    // conv + silu -> HS fp32 + HSb bf16
    conv_kernel<<<(BL_ * DI_) / 256, 256, 0, stream>>>(P, conv_w, conv_b, HS, HSb);

    // ssm projection as MFMA GEMM: SP[2048][128] = HSb @ XPpad^T, split-K x4 atomic
    hipMemsetAsync(SPb, 0, (size_t)BL_ * SPW * 4, stream);
    gemm_bf16<0, 1, float><<<dim3(16, 1, 4), 256, 0, stream>>>(
        HSb, XPpad, SPb, BL_, SPW, DI_ / 4, DI_, DI_, SPW);

    // dt -> DT
    dt_kernel<<<(BL_ * DI_) / 256, 256, 0, stream>>>(SPb, dtwT, dt_b, DTb);

    // chunked scan (C=64 chunks of 16)
    scan_pass1<<<(B_ * C_ * DI_) / 256, 256, 0, stream>>>(DTb, HS, SPb, A_log, Aprod, Bacc);
    scan_pass2<<<(B_ * DI_ * N_) / 256, 256, 0, stream>>>(Aprod, Bacc, Sinit);
    scan_pass3<<<(B_ * C_ * DI_) / 256, 256, 0, stream>>>(
        DTb, HS, SPb, P, A_log, Dvec, Sinit, Yb);

    // G4: U2b = silu(Y @ w_oup^T)   [2048 x 6144], K=1536
    gemm_bf16<1, 0, __bf16><<<dim3(16, 48, 1), 256, 0, stream>>>(
        Yb, woup_b, U2b, BL_, DOUT_, DI_, DI_, DI_, DOUT_);

    // G5: out = U2 @ w_odown^T  fp32 atomic, split-K x8   [2048 x 768], K=6144
    hipMemsetAsync(out, 0, (size_t)BL_ * H_ * 4, stream);
    gemm_bf16<0, 1, float><<<dim3(16, 6, 8), 256, 0, stream>>>(
        U2b, wodown_b, out, BL_, H_, DOUT_ / 8, DOUT_, DOUT_, H_);
}